// Round 13
// baseline (87.389 us; speedup 1.0000x reference)
//
#include <hip/hip_runtime.h>

#define NB   8192
#define NT   2048
#define OBS  30
#define LCH  128              // chunk length (phase 2 ring reuses j&31)
#define CCH  16               // chunks per row
#define RPB  8                // rows per block
#define NTHR 256              // 4 waves
#define CSTR 132              // chunk record stride in floats (33 float4)

// One recurrence step on a 32-slot register ring, 6 accumulator chains.
// Invariant: before step t, state s_t[i] lives at r[(t+i)&31], i=0..29.
// j == t mod 32 must be a compile-time constant (callers fully unroll).
__device__ __forceinline__ float step6(float (&r)[32], const float (&wx)[OBS],
                                       int j, float uwf) {
  float a0 = fmaf(wx[0], r[(j + 0) & 31], uwf);
  float a1 = wx[1] * r[(j + 1) & 31];
  float a2 = wx[2] * r[(j + 2) & 31];
  float a3 = wx[3] * r[(j + 3) & 31];
  float a4 = wx[4] * r[(j + 4) & 31];
  float a5 = wx[5] * r[(j + 5) & 31];
  #pragma unroll
  for (int i = 6; i < OBS; i += 6) {
    a0 = fmaf(wx[i],     r[(j + i)     & 31], a0);
    a1 = fmaf(wx[i + 1], r[(j + i + 1) & 31], a1);
    a2 = fmaf(wx[i + 2], r[(j + i + 2) & 31], a2);
    a3 = fmaf(wx[i + 3], r[(j + i + 3) & 31], a3);
    a4 = fmaf(wx[i + 4], r[(j + i + 4) & 31], a4);
    a5 = fmaf(wx[i + 5], r[(j + i + 5) & 31], a5);
  }
  float out = ((a0 + a1) + (a2 + a3)) + (a4 + a5);
  r[(j + 30) & 31] = out;
  return out;
}

// 30-tap dot against broadcast state, 3 accumulator chains.
__device__ __forceinline__ float dot30(const float (&c)[OBS],
                                       const float (&sv)[32], float p) {
  float a0 = fmaf(c[0], sv[0], p);
  float a1 = c[1] * sv[1];
  float a2 = c[2] * sv[2];
  #pragma unroll
  for (int i = 3; i < OBS; i += 3) {
    a0 = fmaf(c[i],     sv[i],     a0);
    a1 = fmaf(c[i + 1], sv[i + 1], a1);
    a2 = fmaf(c[i + 2], sv[i + 2], a2);
  }
  return a0 + (a1 + a2);
}

// Fully fused. Block: 256 threads (4 waves) own 8 rows; row = 16 chunks of 128.
// Phase 2: thread <-> chunk (tid<128). Phase 3: 32-lane group <-> row; lane k
// owns outputs t=4k..4k+3 of each chunk (4 C rows in regs); one 8xb128 state
// broadcast per 256 outputs. s_next[i] = out[98+i] (last 30 of the chunk).
__global__ void __launch_bounds__(NTHR, 2)
k_fused(const float* __restrict__ u, const float* __restrict__ x0,
        const float* __restrict__ Wx, const float* __restrict__ Wf,
        float* __restrict__ out) {
  __shared__ float tile[RPB * CCH * CSTR];  // 67.6 KB; first 128*33 floats = Cb
  __shared__ float sbuf[RPB * 32];          // per-row running state slot
  const int tid  = threadIdx.x;
  const int wv   = tid >> 6;
  const int g    = tid >> 5;                // row group 0..7
  const int k    = tid & 31;
  const int row0 = blockIdx.x * RPB;

  float wx[OBS];
  #pragma unroll
  for (int i = 0; i < OBS; ++i) wx[i] = Wx[i];
  const float wf = Wf[0];
  float x0v = (k < OBS) ? x0[(size_t)(row0 + g) * OBS + k] : 0.f;

  // ---- issue all u loads early (land while C is computed)
  float4 stg[16];
  const float* ub = u + (size_t)row0 * NT;
  #pragma unroll
  for (int i = 0; i < 16; ++i) {
    int v = i * NTHR + tid, rr = v >> 9, p = v & 511;
    stg[i] = *(const float4*)(ub + (size_t)rr * NT + 4 * p);
  }

  // ---- C[t][i] (t<128, i<30), wave 0 only: lane i runs unit-state chain e_i.
  // Written into the tile's low region (Cb overlay), stride 33.
  if (wv == 0) {
    float r[32];
    #pragma unroll
    for (int i = 0; i < 32; ++i) r[i] = (tid < OBS && i == tid) ? 1.f : 0.f;
    #pragma unroll
    for (int q = 0; q < 32; ++q)
      #pragma unroll
      for (int e = 0; e < 4; ++e) {
        float o = step6(r, wx, (4 * q + e) & 31, 0.f);
        if (tid < OBS) tile[(4 * q + e) * 33 + tid] = o;
      }
  }
  __syncthreads();

  // ---- my 4 C rows (t = 4k..4k+3) into registers; init state slot from x0
  float c0[OBS], c1[OBS], c2[OBS], c3[OBS];
  #pragma unroll
  for (int i = 0; i < OBS; ++i) c0[i] = tile[(4 * k + 0) * 33 + i];
  #pragma unroll
  for (int i = 0; i < OBS; ++i) c1[i] = tile[(4 * k + 1) * 33 + i];
  #pragma unroll
  for (int i = 0; i < OBS; ++i) c2[i] = tile[(4 * k + 2) * 33 + i];
  #pragma unroll
  for (int i = 0; i < OBS; ++i) c3[i] = tile[(4 * k + 3) * 33 + i];
  sbuf[g * 32 + k] = x0v;                   // sl[30],[31] = 0 (never dotted)
  __syncthreads();                          // Cb consumed; tile reusable

  // ---- stage u chunk-major: tile[(row*CCH+chunk)*CSTR + t]
  #pragma unroll
  for (int i = 0; i < 16; ++i) {
    int v = i * NTHR + tid, rr = v >> 9, p = v & 511;
    int c = p >> 5, q = p & 31;
    *(float4*)(&tile[(rr * CCH + c) * CSTR + 4 * q]) = stg[i];
  }
  __syncthreads();

  // ---- phase 2: zero-init particular recurrence; thread <-> chunk (128 st)
  if (tid < RPB * CCH) {
    float r[32];
    #pragma unroll
    for (int i = 0; i < 32; ++i) r[i] = 0.f;
    float* tc = &tile[tid * CSTR];
    #pragma unroll
    for (int q = 0; q < 32; ++q) {
      float4 u4 = *(const float4*)(tc + 4 * q);
      float4 o4;
      o4.x = step6(r, wx, (4 * q + 0) & 31, wf * u4.x);
      o4.y = step6(r, wx, (4 * q + 1) & 31, wf * u4.y);
      o4.z = step6(r, wx, (4 * q + 2) & 31, wf * u4.z);
      o4.w = step6(r, wx, (4 * q + 3) & 31, wf * u4.w);
      *(float4*)(tc + 4 * q) = o4;
    }
  }
  __syncthreads();

  // ---- phase 3: serial chunk scan + correction; group g owns row row0+g
  float* sl = &sbuf[g * 32];
  const float* trow = &tile[(g * CCH) * CSTR];
  float* orow = out + (size_t)(row0 + g) * NT;
  #pragma unroll 1
  for (int c = 0; c < CCH; ++c) {
    float sv[32];
    #pragma unroll
    for (int q = 0; q < 8; ++q) {           // broadcast b128 per group slot
      float4 v = *(const float4*)(sl + 4 * q);
      sv[4 * q] = v.x; sv[4 * q + 1] = v.y;
      sv[4 * q + 2] = v.z; sv[4 * q + 3] = v.w;
    }
    float4 p4 = *(const float4*)(&trow[c * CSTR + 4 * k]);  // particular
    float o0 = dot30(c0, sv, p4.x);         // true out, t = c*128 + 4k + e
    float o1 = dot30(c1, sv, p4.y);
    float o2 = dot30(c2, sv, p4.z);
    float o3 = dot30(c3, sv, p4.w);
    // s_next[i] = out[98+i]: lanes 24..31 publish (masked, aligned b64s)
    if (k >= 25) *(float2*)(&sl[4 * k - 98]) = make_float2(o0, o1);
    if (k >= 24) *(float2*)(&sl[4 * k - 96]) = make_float2(o2, o3);
    *(float4*)(&orow[c * LCH + 4 * k]) = make_float4(o0, o1, o2, o3);
    __builtin_amdgcn_wave_barrier();        // fence slot writes vs next reads
  }
}

extern "C" void kernel_launch(void* const* d_in, const int* in_sizes, int n_in,
                              void* d_out, int out_size, void* d_ws, size_t ws_size,
                              hipStream_t stream) {
  const float* u  = (const float*)d_in[0];
  const float* x0 = (const float*)d_in[1];
  const float* Wx = (const float*)d_in[2];
  const float* Wf = (const float*)d_in[3];
  float* out = (float*)d_out;

  hipLaunchKernelGGL(k_fused, dim3(NB / RPB), dim3(NTHR), 0, stream,
                     u, x0, Wx, Wf, out);
}

// Round 14
// 55.395 us; speedup vs baseline: 1.5776x; 1.5776x over previous
//
#include <hip/hip_runtime.h>

#define NB   8192
#define NT   2048
#define OBS  30
#define CCH  32               // 64-long chunks per row
#define RPB  8                // rows per block
#define NTHR 256              // 4 waves; wave wv owns rows 2wv, 2wv+1 end-to-end
#define CSTR 68               // chunk record stride (17 float4)

// One recurrence step on a 32-slot register ring, 6 accumulator chains.
// Invariant: before step t, state s_t[i] lives at r[(t+i)&31], i=0..29.
// j == t mod 32 must be a compile-time constant (callers fully unroll).
__device__ __forceinline__ float step6(float (&r)[32], const float (&wx)[OBS],
                                       int j, float uwf) {
  float a0 = fmaf(wx[0], r[(j + 0) & 31], uwf);
  float a1 = wx[1] * r[(j + 1) & 31];
  float a2 = wx[2] * r[(j + 2) & 31];
  float a3 = wx[3] * r[(j + 3) & 31];
  float a4 = wx[4] * r[(j + 4) & 31];
  float a5 = wx[5] * r[(j + 5) & 31];
  #pragma unroll
  for (int i = 6; i < OBS; i += 6) {
    a0 = fmaf(wx[i],     r[(j + i)     & 31], a0);
    a1 = fmaf(wx[i + 1], r[(j + i + 1) & 31], a1);
    a2 = fmaf(wx[i + 2], r[(j + i + 2) & 31], a2);
    a3 = fmaf(wx[i + 3], r[(j + i + 3) & 31], a3);
    a4 = fmaf(wx[i + 4], r[(j + i + 4) & 31], a4);
    a5 = fmaf(wx[i + 5], r[(j + i + 5) & 31], a5);
  }
  float out = ((a0 + a1) + (a2 + a3)) + (a4 + a5);
  r[(j + 30) & 31] = out;
  return out;
}

// Fully fused, wave-decoupled. Block: 256 threads (4 waves) own 8 rows.
// Each wave privately: loads its 2 rows of u, stages them, runs the 64
// zero-init chunk recurrences (lane <-> chunk), then the serial chunk scan
// + correction for its 2 rows (32-lane group <-> row; lane k owns outputs
// t=2k,2k+1). Only block-wide sync: publishing the Cb transpose.
__global__ void __launch_bounds__(NTHR, 2)
k_fused(const float* __restrict__ u, const float* __restrict__ x0,
        const float* __restrict__ Wx, const float* __restrict__ Wf,
        float* __restrict__ out) {
  __shared__ float tile[RPB * CCH * CSTR];  // 69.6 KB: [row*32+chunk][68]
  __shared__ float Cb[64 * 33];             // 8.4 KB: C[t][i], stride 33
  __shared__ float sbuf[RPB * 32];          // per-row running state slot
  const int tid  = threadIdx.x;
  const int wv   = tid >> 6;
  const int lane = tid & 63;
  const int half = lane >> 5;
  const int k    = lane & 31;
  const int row0 = blockIdx.x * RPB;
  const int lr   = wv * 2 + half;           // phase-3 local row
  const int row  = row0 + lr;

  float wx[OBS];
  #pragma unroll
  for (int i = 0; i < OBS; ++i) wx[i] = Wx[i];
  const float wf = Wf[0];

  // ---- wave-local u loads: this wave's 2 rows (land while C is computed)
  float4 stg[16];
  const float* ub = u + ((size_t)row0 + 2 * wv) * NT;
  #pragma unroll
  for (int i = 0; i < 16; ++i) {
    int v = i * 64 + lane, rr = v >> 9, p = v & 511;
    stg[i] = *(const float4*)(ub + (size_t)rr * NT + 4 * p);
  }

  // ---- C[t][i] (t<64, i<30): homogeneous out at step t from unit state e_i.
  // Redundant per wave (lane&31 = column); wave-0 lanes 0..29 write Cb.
  {
    float r[32];
    #pragma unroll
    for (int i = 0; i < 32; ++i) r[i] = (k < OBS && i == k) ? 1.f : 0.f;
    #pragma unroll
    for (int q = 0; q < 16; ++q)
      #pragma unroll
      for (int e = 0; e < 4; ++e) {
        float o = step6(r, wx, (4 * q + e) & 31, 0.f);
        if (tid < OBS) Cb[(4 * q + e) * 33 + tid] = o;
      }
  }
  // x0 -> this wave's two state slots
  if (k < OBS) sbuf[lr * 32 + k] = x0[(size_t)row * OBS + k];

  // ---- wave-local staging: chunk-major into this wave's 64 records
  float* sub = &tile[(wv * 2 * CCH) * CSTR];
  #pragma unroll
  for (int i = 0; i < 16; ++i) {
    int v = i * 64 + lane, rr = v >> 9, p = v & 511;
    int c = p >> 4, q = p & 15;
    *(float4*)(&sub[(rr * CCH + c) * CSTR + 4 * q]) = stg[i];
  }
  __syncthreads();                          // publish Cb (only block-wide sync)

  // ---- my two C rows (t = 2k, 2k+1); DS reads in the VALU-idle window
  float c0[OBS], c1[OBS];
  #pragma unroll
  for (int i = 0; i < OBS; ++i) c0[i] = Cb[(2 * k) * 33 + i];
  #pragma unroll
  for (int i = 0; i < OBS; ++i) c1[i] = Cb[(2 * k + 1) * 33 + i];

  // ---- phase 2 (wave-local): zero-init particular recurrence; lane <-> chunk
  {
    float r[32];
    #pragma unroll
    for (int i = 0; i < 32; ++i) r[i] = 0.f;
    float* tc = &sub[lane * CSTR];
    #pragma unroll
    for (int q = 0; q < 16; ++q) {
      float4 u4 = *(const float4*)(tc + 4 * q);
      float4 o4;
      o4.x = step6(r, wx, (4 * q + 0) & 31, wf * u4.x);
      o4.y = step6(r, wx, (4 * q + 1) & 31, wf * u4.y);
      o4.z = step6(r, wx, (4 * q + 2) & 31, wf * u4.z);
      o4.w = step6(r, wx, (4 * q + 3) & 31, wf * u4.w);
      *(float4*)(tc + 4 * q) = o4;
    }
  }
  __builtin_amdgcn_wave_barrier();          // order p2 DS writes vs p3 reads

  // ---- phase 3 (wave-local): serial chunk scan + correction for 2 rows
  float* sl = &sbuf[lr * 32];
  const float* trow = &sub[half * CCH * CSTR];
  float* orow = out + (size_t)row * NT;
  float2 pq = *(const float2*)(&trow[2 * k]);   // prefetch chunk 0 particular
  #pragma unroll 1
  for (int c = 0; c < CCH; ++c) {
    float sv[32];
    #pragma unroll
    for (int q = 0; q < 8; ++q) {           // broadcast b128 (one slot/group)
      float4 v = *(const float4*)(sl + 4 * q);
      sv[4 * q] = v.x; sv[4 * q + 1] = v.y;
      sv[4 * q + 2] = v.z; sv[4 * q + 3] = v.w;
    }
    float2 pqn = pq;
    if (c + 1 < CCH)                        // next chunk's particular:
      pqn = *(const float2*)(&trow[(c + 1) * CSTR + 2 * k]);  // off serial path
    float a0 = fmaf(c0[0], sv[0], pq.x);
    float a1 = c0[1] * sv[1];
    float a2 = c0[2] * sv[2];
    float b0 = fmaf(c1[0], sv[0], pq.y);
    float b1 = c1[1] * sv[1];
    float b2 = c1[2] * sv[2];
    #pragma unroll
    for (int i = 3; i < OBS; i += 3) {
      a0 = fmaf(c0[i],     sv[i],     a0);
      a1 = fmaf(c0[i + 1], sv[i + 1], a1);
      a2 = fmaf(c0[i + 2], sv[i + 2], a2);
      b0 = fmaf(c1[i],     sv[i],     b0);
      b1 = fmaf(c1[i + 1], sv[i + 1], b1);
      b2 = fmaf(c1[i + 2], sv[i + 2], b2);
    }
    float t0 = a0 + (a1 + a2);              // true out, t = c*64 + 2k
    float t1 = b0 + (b1 + b2);              // true out, t = c*64 + 2k+1
    if (k >= 17)                            // s_next[i] = out[34+i]
      *(float2*)(&sl[2 * k - 34]) = make_float2(t0, t1);
    *(float2*)(&orow[c * 64 + 2 * k]) = make_float2(t0, t1);  // 256B/group
    pq = pqn;
    __builtin_amdgcn_wave_barrier();        // fence slot write vs next reads
  }
}

extern "C" void kernel_launch(void* const* d_in, const int* in_sizes, int n_in,
                              void* d_out, int out_size, void* d_ws, size_t ws_size,
                              hipStream_t stream) {
  const float* u  = (const float*)d_in[0];
  const float* x0 = (const float*)d_in[1];
  const float* Wx = (const float*)d_in[2];
  const float* Wf = (const float*)d_in[3];
  float* out = (float*)d_out;

  hipLaunchKernelGGL(k_fused, dim3(NB / RPB), dim3(NTHR), 0, stream,
                     u, x0, Wx, Wf, out);
}

// Round 15
// 46.382 us; speedup vs baseline: 1.8841x; 1.1943x over previous
//
#include <hip/hip_runtime.h>

#define NB   8192
#define NT   2048
#define OBS  30
#define CCH  32               // 64-long chunks per row
#define RPB  8                // rows per block
#define NTHR 256              // 4 waves; wave wv owns rows 2wv, 2wv+1 end-to-end
#define CSTR 68               // chunk record stride (17 float4)

typedef float v2f __attribute__((ext_vector_type(2)));

// Packed two-step on a 32-slot ring: advances steps t=j, j+1 (j even,
// compile-time). wxp[m] = (wx[m], wx[m-1]), wx[-1]=0; w29 = wx[29].
// x-lane accumulates out_j, y-lane out_{j+1} minus its out_j-feedback tap
// (both share multiplicand r[j+m] -> one v_pk_fma_f32 per tap).
__device__ __forceinline__ v2f step2(float (&r)[32], const v2f (&wxp)[OBS],
                                     float w29, int j, float uw0, float uw1) {
  v2f a0 = {uw0, uw1};
  v2f a1 = {0.f, 0.f};
  v2f a2 = {0.f, 0.f};
  #pragma unroll
  for (int m = 0; m < OBS; m += 3) {
    float r0 = r[(j + m) & 31], r1 = r[(j + m + 1) & 31], r2 = r[(j + m + 2) & 31];
    a0 = __builtin_elementwise_fma(wxp[m],     (v2f){r0, r0}, a0);
    a1 = __builtin_elementwise_fma(wxp[m + 1], (v2f){r1, r1}, a1);
    a2 = __builtin_elementwise_fma(wxp[m + 2], (v2f){r2, r2}, a2);
  }
  v2f A = (a0 + a1) + a2;
  float o0 = A.x;                     // out_j
  float o1 = fmaf(w29, o0, A.y);      // out_{j+1} = A.y + wx[29]*out_j
  r[(j + 30) & 31] = o0;
  r[(j + 31) & 31] = o1;
  return (v2f){o0, o1};
}

// 15-pair packed dot: taps 0..29 against sv pairs, horizontal-reduced, + p.
__device__ __forceinline__ float dot15(const v2f (&cp)[15], const v2f (&sv)[16],
                                       float p) {
  v2f a0 = cp[0] * sv[0];
  v2f a1 = cp[1] * sv[1];
  v2f a2 = cp[2] * sv[2];
  #pragma unroll
  for (int m = 3; m < 15; m += 3) {
    a0 = __builtin_elementwise_fma(cp[m],     sv[m],     a0);
    a1 = __builtin_elementwise_fma(cp[m + 1], sv[m + 1], a1);
    a2 = __builtin_elementwise_fma(cp[m + 2], sv[m + 2], a2);
  }
  v2f A = (a0 + a1) + a2;
  return (A.x + A.y) + p;
}

// Fully fused, wave-decoupled (R14 structure), packed-FMA everywhere.
__global__ void __launch_bounds__(NTHR, 2)
k_fused(const float* __restrict__ u, const float* __restrict__ x0,
        const float* __restrict__ Wx, const float* __restrict__ Wf,
        float* __restrict__ out) {
  __shared__ float tile[RPB * CCH * CSTR];  // 69.6 KB: [row*32+chunk][68]
  __shared__ float Cb[64 * 33];             // 8.4 KB: C[t][i], stride 33
  __shared__ float sbuf[RPB * 32];          // per-row running state slot
  const int tid  = threadIdx.x;
  const int wv   = tid >> 6;
  const int lane = tid & 63;
  const int half = lane >> 5;
  const int k    = lane & 31;
  const int row0 = blockIdx.x * RPB;
  const int lr   = wv * 2 + half;           // phase-3 local row
  const int row  = row0 + lr;

  // taps as packed pairs (wx[m], wx[m-1]); w29 kept scalar for the feedback
  v2f wxp[OBS];
  wxp[0] = (v2f){Wx[0], 0.f};
  #pragma unroll
  for (int m = 1; m < OBS; ++m) wxp[m] = (v2f){Wx[m], Wx[m - 1]};
  const float w29 = wxp[29].x;
  const float wf  = Wf[0];

  // ---- wave-local u loads: this wave's 2 rows (land while C is computed)
  float4 stg[16];
  const float* ub = u + ((size_t)row0 + 2 * wv) * NT;
  #pragma unroll
  for (int i = 0; i < 16; ++i) {
    int v = i * 64 + lane, rr = v >> 9, p = v & 511;
    stg[i] = *(const float4*)(ub + (size_t)rr * NT + 4 * p);
  }

  // ---- C[t][i] (t<64, i<30): homogeneous out at step t from unit state e_i.
  // Redundant per wave (lane&31 = column); wave-0 lanes 0..29 write Cb.
  {
    float r[32];
    #pragma unroll
    for (int i = 0; i < 32; ++i) r[i] = (k < OBS && i == k) ? 1.f : 0.f;
    #pragma unroll
    for (int s = 0; s < 32; ++s) {
      v2f o = step2(r, wxp, w29, (2 * s) & 31, 0.f, 0.f);
      if (tid < OBS) {
        Cb[(2 * s) * 33 + tid]     = o.x;
        Cb[(2 * s + 1) * 33 + tid] = o.y;
      }
    }
  }
  // x0 -> this wave's two state slots (zeros in 30,31: read-but-unused pair)
  sbuf[lr * 32 + k] = (k < OBS) ? x0[(size_t)row * OBS + k] : 0.f;

  // ---- wave-local staging: chunk-major into this wave's 64 records
  float* sub = &tile[(wv * 2 * CCH) * CSTR];
  #pragma unroll
  for (int i = 0; i < 16; ++i) {
    int v = i * 64 + lane, rr = v >> 9, p = v & 511;
    int c = p >> 4, q = p & 15;
    *(float4*)(&sub[(rr * CCH + c) * CSTR + 4 * q]) = stg[i];
  }
  __syncthreads();                          // publish Cb (only block-wide sync)

  // ---- my two C rows (t = 2k, 2k+1) as 15 packed pairs each
  v2f c0p[15], c1p[15];
  #pragma unroll
  for (int m = 0; m < 15; ++m)
    c0p[m] = (v2f){Cb[(2 * k) * 33 + 2 * m], Cb[(2 * k) * 33 + 2 * m + 1]};
  #pragma unroll
  for (int m = 0; m < 15; ++m)
    c1p[m] = (v2f){Cb[(2 * k + 1) * 33 + 2 * m], Cb[(2 * k + 1) * 33 + 2 * m + 1]};

  // ---- phase 2 (wave-local): zero-init particular recurrence; lane <-> chunk
  {
    float r[32];
    #pragma unroll
    for (int i = 0; i < 32; ++i) r[i] = 0.f;
    float* tc = &sub[lane * CSTR];
    #pragma unroll
    for (int q = 0; q < 16; ++q) {
      float4 u4 = *(const float4*)(tc + 4 * q);
      v2f oA = step2(r, wxp, w29, (4 * q)     & 31, wf * u4.x, wf * u4.y);
      v2f oB = step2(r, wxp, w29, (4 * q + 2) & 31, wf * u4.z, wf * u4.w);
      *(float4*)(tc + 4 * q) = make_float4(oA.x, oA.y, oB.x, oB.y);
    }
  }
  __builtin_amdgcn_wave_barrier();          // order p2 DS writes vs p3 reads

  // ---- phase 3 (wave-local): serial chunk scan + correction for 2 rows
  float* sl = &sbuf[lr * 32];
  const float* trow = &sub[half * CCH * CSTR];
  float* orow = out + (size_t)row * NT;
  float2 pq = *(const float2*)(&trow[2 * k]);   // prefetch chunk 0 particular
  #pragma unroll 1
  for (int c = 0; c < CCH; ++c) {
    v2f sv2[16];
    #pragma unroll
    for (int q = 0; q < 8; ++q) {           // broadcast b128 (one slot/group)
      float4 v = *(const float4*)(sl + 4 * q);
      sv2[2 * q]     = (v2f){v.x, v.y};
      sv2[2 * q + 1] = (v2f){v.z, v.w};
    }
    float2 pqn = pq;
    if (c + 1 < CCH)                        // next chunk's particular:
      pqn = *(const float2*)(&trow[(c + 1) * CSTR + 2 * k]);  // off serial path
    float t0 = dot15(c0p, sv2, pq.x);       // true out, t = c*64 + 2k
    float t1 = dot15(c1p, sv2, pq.y);       // true out, t = c*64 + 2k+1
    if (k >= 17)                            // s_next[i] = out[34+i]
      *(float2*)(&sl[2 * k - 34]) = make_float2(t0, t1);
    *(float2*)(&orow[c * 64 + 2 * k]) = make_float2(t0, t1);  // 256B/group
    pq = pqn;
    __builtin_amdgcn_wave_barrier();        // fence slot write vs next reads
  }
}

extern "C" void kernel_launch(void* const* d_in, const int* in_sizes, int n_in,
                              void* d_out, int out_size, void* d_ws, size_t ws_size,
                              hipStream_t stream) {
  const float* u  = (const float*)d_in[0];
  const float* x0 = (const float*)d_in[1];
  const float* Wx = (const float*)d_in[2];
  const float* Wf = (const float*)d_in[3];
  float* out = (float*)d_out;

  hipLaunchKernelGGL(k_fused, dim3(NB / RPB), dim3(NTHR), 0, stream,
                     u, x0, Wx, Wf, out);
}